// Round 1
// baseline (4676.103 us; speedup 1.0000x reference)
//
#include <hip/hip_runtime.h>
#include <math.h>

#define DH 128
#define EPSB 1e-5f

// ---------------- degree / dinv / graph boundaries ----------------

__global__ void k_count(const int* __restrict__ dst, int* __restrict__ deg, int E) {
    int i = blockIdx.x * blockDim.x + threadIdx.x;
    if (i < E) atomicAdd(&deg[dst[i]], 1);
}

__global__ void k_dinv(const int* __restrict__ deg, float* __restrict__ dinv, int N) {
    int i = blockIdx.x * blockDim.x + threadIdx.x;
    if (i < N) dinv[i] = rsqrtf((float)(deg[i] + 1));  // +1 self-loop; always > 0
}

__global__ void k_bounds(const int* __restrict__ batch, int* __restrict__ starts, int N, int G) {
    int i = blockIdx.x * blockDim.x + threadIdx.x;
    if (i < N) {
        int b = batch[i];
        if (i == 0) { starts[0] = 0; starts[G] = N; }
        else if (batch[i - 1] != b) starts[b] = i;
    }
}

// ---------------- GEMM: hs = (X @ W) * dinv[row]; agg seeded = hs ----------------
// 128 rows x 128 cols per block, 256 threads, 8x8 acc/thread, K=128 in 4 chunks of 32.

__launch_bounds__(256)
__global__ void k_gemm(const float* __restrict__ X, const float* __restrict__ W,
                       const float* __restrict__ dinv,
                       float* __restrict__ hs, float* __restrict__ agg, int N)
{
    __shared__ float xT[32][129];   // transposed x tile, +1 pad
    __shared__ float wS[32][128];

    const int t  = threadIdx.x;
    const int tr = t >> 4;          // 0..15  -> rows tr*8..tr*8+7
    const int tc = t & 15;          // 0..15  -> cols tc*8..tc*8+7
    const int rowBase = blockIdx.x * 128;

    float acc[8][8];
#pragma unroll
    for (int i = 0; i < 8; ++i)
#pragma unroll
        for (int j = 0; j < 8; ++j) acc[i][j] = 0.f;

    const int kl = t & 31;   // k lane for x load
    const int rl = t >> 5;   // 0..7

    for (int k0 = 0; k0 < 128; k0 += 32) {
        // stage x tile (transposed)
#pragma unroll
        for (int p = 0; p < 16; ++p) {
            int rloc = p * 8 + rl;
            int gr = rowBase + rloc;
            float v = 0.f;
            if (gr < N) v = X[(size_t)gr * DH + k0 + kl];
            xT[kl][rloc] = v;
        }
        // stage W panel
#pragma unroll
        for (int p = 0; p < 16; ++p) {
            int idx = p * 256 + t;
            int kk = idx >> 7, cc = idx & 127;
            wS[kk][cc] = W[(size_t)(k0 + kk) * DH + cc];
        }
        __syncthreads();
#pragma unroll
        for (int k = 0; k < 32; ++k) {
            float a[8], b[8];
#pragma unroll
            for (int i = 0; i < 8; ++i) a[i] = xT[k][tr * 8 + i];
#pragma unroll
            for (int j = 0; j < 8; ++j) b[j] = wS[k][tc * 8 + j];
#pragma unroll
            for (int i = 0; i < 8; ++i)
#pragma unroll
                for (int j = 0; j < 8; ++j) acc[i][j] += a[i] * b[j];
        }
        __syncthreads();
    }

#pragma unroll
    for (int i = 0; i < 8; ++i) {
        int gr = rowBase + tr * 8 + i;
        if (gr < N) {
            float s = dinv[gr];
            float* hp = hs  + (size_t)gr * DH + tc * 8;
            float* ap = agg + (size_t)gr * DH + tc * 8;
#pragma unroll
            for (int j = 0; j < 8; ++j) { float v = acc[i][j] * s; hp[j] = v; ap[j] = v; }
        }
    }
}

// ---------------- edge scatter: agg[dst] += hs[src] ----------------
// one wave per edge, float2 per lane, native fp32 atomics

__launch_bounds__(256)
__global__ void k_scatter(const float* __restrict__ hs, float* __restrict__ agg,
                          const int* __restrict__ src, const int* __restrict__ dst, int E)
{
    int w = (blockIdx.x * blockDim.x + threadIdx.x) >> 6;
    int lane = threadIdx.x & 63;
    if (w >= E) return;
    int s = src[w], d = dst[w];
    const float2 v = *(const float2*)(hs + (size_t)s * DH + lane * 2);
    float* ap = agg + (size_t)d * DH + lane * 2;
    unsafeAtomicAdd(ap, v.x);
    unsafeAtomicAdd(ap + 1, v.y);
}

// ---------------- post: x_out = relu(BN(agg*dinv + cb)) [+ prev] ----------------

__global__ void k_post(const float4* __restrict__ agg, const float* __restrict__ dinv,
                       const float* __restrict__ cb, const float* __restrict__ bm,
                       const float* __restrict__ bv, const float* __restrict__ bg,
                       const float* __restrict__ bb, const float4* __restrict__ prev,
                       float4* __restrict__ xout, int N)
{
    int i = blockIdx.x * blockDim.x + threadIdx.x;   // over N*32 float4
    if (i >= N * 32) return;
    int node = i >> 5;
    int f4 = (i & 31) * 4;
    float s = dinv[node];
    float4 a = agg[i];
    float r[4] = {a.x, a.y, a.z, a.w};
    float o[4];
#pragma unroll
    for (int j = 0; j < 4; ++j) {
        int f = f4 + j;
        float val = r[j] * s + cb[f];
        val = (val - bm[f]) * rsqrtf(bv[f] + EPSB) * bg[f] + bb[f];
        o[j] = fmaxf(val, 0.f);
    }
    if (prev) {
        float4 p = prev[i];
        o[0] += p.x; o[1] += p.y; o[2] += p.z; o[3] += p.w;
    }
    float4 ov = make_float4(o[0], o[1], o[2], o[3]);
    xout[i] = ov;
}

// ---------------- fused pool (mean+max per graph) + 3-layer MLP head ----------------
// one block of 128 threads per graph

__launch_bounds__(128)
__global__ void k_pool_mlp(const float* __restrict__ x, const int* __restrict__ starts,
                           const float* __restrict__ L1w, const float* __restrict__ L1b,
                           const float* __restrict__ L2w, const float* __restrict__ L2b,
                           const float* __restrict__ L3w, const float* __restrict__ L3b,
                           float* __restrict__ out)
{
    int g = blockIdx.x, t = threadIdx.x;
    int s0 = starts[g], s1 = starts[g + 1];
    float sum = 0.f, mx = -INFINITY;
    for (int i = s0; i < s1; ++i) {
        float v = x[(size_t)i * DH + t];
        sum += v;
        mx = fmaxf(mx, v);
    }
    __shared__ float h[256];
    h[t] = sum / (float)(s1 - s0);
    h[128 + t] = mx;
    __syncthreads();

    float a = L1b[t];
    for (int k = 0; k < 256; ++k) a += h[k] * L1w[k * DH + t];
    __shared__ float h1[128];
    h1[t] = fmaxf(a, 0.f);
    __syncthreads();

    __shared__ float h2[64];
    if (t < 64) {
        float a2 = L2b[t];
        for (int k = 0; k < 128; ++k) a2 += h1[k] * L2w[k * 64 + t];
        h2[t] = fmaxf(a2, 0.f);
    }
    __syncthreads();

    if (t < 64) {
        float p = h2[t] * L3w[t];
#pragma unroll
        for (int off = 32; off > 0; off >>= 1) p += __shfl_down(p, off, 64);
        if (t == 0) out[g] = p + L3b[0];
    }
}

// ---------------- launch ----------------

extern "C" void kernel_launch(void* const* d_in, const int* in_sizes, int n_in,
                              void* d_out, int out_size, void* d_ws, size_t ws_size,
                              hipStream_t stream)
{
    const float* x     = (const float*)d_in[0];
    const int*   ei    = (const int*)d_in[1];
    const int*   batch = (const int*)d_in[2];
    const int N = in_sizes[0] / DH;
    const int E = in_sizes[1] / 2;
    const int G = out_size;
    const int* src = ei;
    const int* dst = ei + E;

    const float* W[3]  = {(const float*)d_in[3],  (const float*)d_in[9],  (const float*)d_in[15]};
    const float* cb[3] = {(const float*)d_in[4],  (const float*)d_in[10], (const float*)d_in[16]};
    const float* bg[3] = {(const float*)d_in[5],  (const float*)d_in[11], (const float*)d_in[17]};
    const float* bt[3] = {(const float*)d_in[6],  (const float*)d_in[12], (const float*)d_in[18]};
    const float* bm[3] = {(const float*)d_in[7],  (const float*)d_in[13], (const float*)d_in[19]};
    const float* bv[3] = {(const float*)d_in[8],  (const float*)d_in[14], (const float*)d_in[20]};
    const float* L1w = (const float*)d_in[21]; const float* L1b = (const float*)d_in[22];
    const float* L2w = (const float*)d_in[23]; const float* L2b = (const float*)d_in[24];
    const float* L3w = (const float*)d_in[25]; const float* L3b = (const float*)d_in[26];

    char* wsp = (char*)d_ws;
    size_t big = (size_t)N * DH * sizeof(float);
    float* P0 = (float*)wsp;  wsp += big;
    float* P1 = (float*)wsp;  wsp += big;
    float* P2 = (float*)wsp;  wsp += big;
    float* dinv = (float*)wsp; wsp += (size_t)N * sizeof(float);
    int*   deg  = (int*)wsp;   wsp += (size_t)N * sizeof(int);
    int*   starts = (int*)wsp; wsp += (size_t)(G + 1) * sizeof(int);

    hipMemsetAsync(deg, 0, (size_t)N * sizeof(int), stream);
    k_count<<<(E + 255) / 256, 256, 0, stream>>>(dst, deg, E);
    k_dinv<<<(N + 255) / 256, 256, 0, stream>>>(deg, dinv, N);
    k_bounds<<<(N + 255) / 256, 256, 0, stream>>>(batch, starts, N, G);

    // buffer rotation:
    // L0: X=input -> hs=P0, agg=P1, post(P1, prev=null) -> xout=P0
    // L1: X=P0    -> hs=P1, agg=P2, post(P2, prev=P0)   -> xout=P1
    // L2: X=P1    -> hs=P0, agg=P2, post(P2, prev=P1)   -> xout=P0
    const float* Xs[3]    = {x, P0, P1};
    float* hsb[3]         = {P0, P1, P0};
    float* aggb[3]        = {P1, P2, P2};
    const float* prevb[3] = {nullptr, P0, P1};
    float* xoutb[3]       = {P0, P1, P0};

    int gemmGrid = (N + 127) / 128;
    int postGrid = (N * 32 + 255) / 256;
    int scatGrid = (E + 3) / 4;   // 4 waves (edges) per 256-thread block

    for (int l = 0; l < 3; ++l) {
        k_gemm<<<gemmGrid, 256, 0, stream>>>(Xs[l], W[l], dinv, hsb[l], aggb[l], N);
        k_scatter<<<scatGrid, 256, 0, stream>>>(hsb[l], aggb[l], src, dst, E);
        k_post<<<postGrid, 256, 0, stream>>>((const float4*)aggb[l], dinv,
                                             cb[l], bm[l], bv[l], bg[l], bt[l],
                                             (const float4*)prevb[l], (float4*)xoutb[l], N);
    }

    k_pool_mlp<<<G, 128, 0, stream>>>(xoutb[2], starts, L1w, L1b, L2w, L2b, L3w, L3b,
                                      (float*)d_out);
}

// Round 2
// 1240.037 us; speedup vs baseline: 3.7709x; 3.7709x over previous
//
#include <hip/hip_runtime.h>
#include <math.h>

#define DH 128
#define EPSB 1e-5f

// ---------------- degree / dinv / graph boundaries ----------------

__global__ void k_count(const int* __restrict__ dst, int* __restrict__ deg, int E) {
    int i = blockIdx.x * blockDim.x + threadIdx.x;
    if (i < E) atomicAdd(&deg[dst[i]], 1);
}

__global__ void k_dinv(const int* __restrict__ deg, float* __restrict__ dinv, int N) {
    int i = blockIdx.x * blockDim.x + threadIdx.x;
    if (i < N) dinv[i] = rsqrtf((float)(deg[i] + 1));  // +1 self-loop; always > 0
}

__global__ void k_bounds(const int* __restrict__ batch, int* __restrict__ starts, int N, int G) {
    int i = blockIdx.x * blockDim.x + threadIdx.x;
    if (i < N) {
        int b = batch[i];
        if (i == 0) { starts[0] = 0; starts[G] = N; }
        else if (batch[i - 1] != b) starts[b] = i;
    }
}

// ---------------- exclusive scan of deg -> rowptr (3-pass) ----------------
// pass 1: per-block (1024 elems) local exclusive scan + block sums

__launch_bounds__(256)
__global__ void k_scan1(const int* __restrict__ deg, int* __restrict__ rowptr,
                        int* __restrict__ bsum, int N)
{
    __shared__ int wsum[4], woff[4];
    const int t = threadIdx.x;
    const int lane = t & 63, wid = t >> 6;
    const int base = blockIdx.x * 1024 + t * 4;

    int v[4], local = 0;
#pragma unroll
    for (int j = 0; j < 4; ++j) {
        v[j] = (base + j < N) ? deg[base + j] : 0;
        local += v[j];
    }
    // inclusive wave scan of `local`
    int sc = local;
#pragma unroll
    for (int off = 1; off < 64; off <<= 1) {
        int n = __shfl_up(sc, off, 64);
        if (lane >= off) sc += n;
    }
    if (lane == 63) wsum[wid] = sc;
    __syncthreads();
    if (t == 0) {
        int r = 0;
#pragma unroll
        for (int i = 0; i < 4; ++i) { woff[i] = r; r += wsum[i]; }
        bsum[blockIdx.x] = r;
    }
    __syncthreads();
    int run = woff[wid] + sc - local;   // exclusive prefix for this thread's chunk
#pragma unroll
    for (int j = 0; j < 4; ++j) {
        if (base + j < N) rowptr[base + j] = run;
        run += v[j];
    }
}

// pass 2: scan block sums (B <= 256) in one block
__global__ void k_scan2(int* __restrict__ bsum, int B) {
    __shared__ int s[256];
    int t = threadIdx.x;
    s[t] = (t < B) ? bsum[t] : 0;
    __syncthreads();
    for (int off = 1; off < 256; off <<= 1) {
        int v = (t >= off) ? s[t - off] : 0;
        __syncthreads();
        s[t] += v;
        __syncthreads();
    }
    if (t < B) bsum[t] = (t == 0) ? 0 : s[t - 1];
}

// pass 3: add block offsets, set rowptr[N]
__launch_bounds__(256)
__global__ void k_scan3(int* __restrict__ rowptr, const int* __restrict__ bsum, int N, int E) {
    int t = threadIdx.x;
    int base = blockIdx.x * 1024 + t * 4;
    int off = bsum[blockIdx.x];
#pragma unroll
    for (int j = 0; j < 4; ++j)
        if (base + j < N) rowptr[base + j] += off;
    if (blockIdx.x == 0 && t == 0) rowptr[N] = E;
}

// ---------------- CSR fill: csr_src[cursor[dst]++] = src ----------------

__global__ void k_fill(const int* __restrict__ src, const int* __restrict__ dst,
                       int* __restrict__ cursor, int* __restrict__ csr_src, int E)
{
    int e = blockIdx.x * blockDim.x + threadIdx.x;
    if (e < E) {
        int d = dst[e];
        int pos = atomicAdd(&cursor[d], 1);
        csr_src[pos] = src[e];
    }
}

// ---------------- GEMM: hs = (X @ W) * dinv[row] ----------------
// 128 rows x 128 cols per block, 256 threads, 8x8 acc/thread, K=128 in 4 chunks of 32.

__launch_bounds__(256)
__global__ void k_gemm(const float* __restrict__ X, const float* __restrict__ W,
                       const float* __restrict__ dinv, float* __restrict__ hs, int N)
{
    __shared__ float xT[32][129];   // transposed x tile, +1 pad
    __shared__ float wS[32][128];

    const int t  = threadIdx.x;
    const int tr = t >> 4;          // 0..15  -> rows tr*8..tr*8+7
    const int tc = t & 15;          // 0..15  -> cols tc*8..tc*8+7
    const int rowBase = blockIdx.x * 128;

    float acc[8][8];
#pragma unroll
    for (int i = 0; i < 8; ++i)
#pragma unroll
        for (int j = 0; j < 8; ++j) acc[i][j] = 0.f;

    const int kl = t & 31;   // k lane for x load
    const int rl = t >> 5;   // 0..7

    for (int k0 = 0; k0 < 128; k0 += 32) {
#pragma unroll
        for (int p = 0; p < 16; ++p) {
            int rloc = p * 8 + rl;
            int gr = rowBase + rloc;
            float v = 0.f;
            if (gr < N) v = X[(size_t)gr * DH + k0 + kl];
            xT[kl][rloc] = v;
        }
#pragma unroll
        for (int p = 0; p < 16; ++p) {
            int idx = p * 256 + t;
            int kk = idx >> 7, cc = idx & 127;
            wS[kk][cc] = W[(size_t)(k0 + kk) * DH + cc];
        }
        __syncthreads();
#pragma unroll
        for (int k = 0; k < 32; ++k) {
            float a[8], b[8];
#pragma unroll
            for (int i = 0; i < 8; ++i) a[i] = xT[k][tr * 8 + i];
#pragma unroll
            for (int j = 0; j < 8; ++j) b[j] = wS[k][tc * 8 + j];
#pragma unroll
            for (int i = 0; i < 8; ++i)
#pragma unroll
                for (int j = 0; j < 8; ++j) acc[i][j] += a[i] * b[j];
        }
        __syncthreads();
    }

#pragma unroll
    for (int i = 0; i < 8; ++i) {
        int gr = rowBase + tr * 8 + i;
        if (gr < N) {
            float s = dinv[gr];
            float* hp = hs + (size_t)gr * DH + tc * 8;
#pragma unroll
            for (int j = 0; j < 8; ++j) hp[j] = acc[i][j] * s;
        }
    }
}

// ---------------- gather + fused post ----------------
// one wave per dst node; out[d] = relu(BN(dinv[d]*(hs[d]+sum_src hs[src]) + cb)) [+ prev]

__launch_bounds__(256)
__global__ void k_gather(const float* __restrict__ hs, const int* __restrict__ rowptr,
                         const int* __restrict__ csr_src, const float* __restrict__ dinv,
                         const float* __restrict__ cb, const float* __restrict__ bm,
                         const float* __restrict__ bv, const float* __restrict__ bg,
                         const float* __restrict__ bb, const float* __restrict__ prev,
                         float* __restrict__ xout, int N)
{
    const int w = (blockIdx.x * blockDim.x + threadIdx.x) >> 6;   // node
    const int lane = threadIdx.x & 63;
    if (w >= N) return;
    const int f = lane * 2;
    const int e0 = rowptr[w], e1 = rowptr[w + 1];

    float2 acc = *(const float2*)(hs + (size_t)w * DH + f);   // self-loop term

    for (int base = e0; base < e1; base += 64) {
        int cnt = e1 - base; if (cnt > 64) cnt = 64;
        int idx = (lane < cnt) ? csr_src[base + lane] : 0;
        for (int i = 0; i < cnt; ++i) {
            int s = __shfl(idx, i, 64);
            const float2 v = *(const float2*)(hs + (size_t)s * DH + f);
            acc.x += v.x; acc.y += v.y;
        }
    }

    const float sc = dinv[w];
    float o0 = acc.x * sc + cb[f];
    float o1 = acc.y * sc + cb[f + 1];
    o0 = (o0 - bm[f])     * rsqrtf(bv[f]     + EPSB) * bg[f]     + bb[f];
    o1 = (o1 - bm[f + 1]) * rsqrtf(bv[f + 1] + EPSB) * bg[f + 1] + bb[f + 1];
    o0 = fmaxf(o0, 0.f);
    o1 = fmaxf(o1, 0.f);
    if (prev) {
        const float2 p = *(const float2*)(prev + (size_t)w * DH + f);
        o0 += p.x; o1 += p.y;
    }
    *(float2*)(xout + (size_t)w * DH + f) = make_float2(o0, o1);
}

// ---------------- fused pool (mean+max per graph) + 3-layer MLP head ----------------

__launch_bounds__(128)
__global__ void k_pool_mlp(const float* __restrict__ x, const int* __restrict__ starts,
                           const float* __restrict__ L1w, const float* __restrict__ L1b,
                           const float* __restrict__ L2w, const float* __restrict__ L2b,
                           const float* __restrict__ L3w, const float* __restrict__ L3b,
                           float* __restrict__ out)
{
    int g = blockIdx.x, t = threadIdx.x;
    int s0 = starts[g], s1 = starts[g + 1];
    float sum = 0.f, mx = -INFINITY;
    for (int i = s0; i < s1; ++i) {
        float v = x[(size_t)i * DH + t];
        sum += v;
        mx = fmaxf(mx, v);
    }
    __shared__ float h[256];
    h[t] = sum / (float)(s1 - s0);
    h[128 + t] = mx;
    __syncthreads();

    float a = L1b[t];
    for (int k = 0; k < 256; ++k) a += h[k] * L1w[k * DH + t];
    __shared__ float h1[128];
    h1[t] = fmaxf(a, 0.f);
    __syncthreads();

    __shared__ float h2[64];
    if (t < 64) {
        float a2 = L2b[t];
        for (int k = 0; k < 128; ++k) a2 += h1[k] * L2w[k * 64 + t];
        h2[t] = fmaxf(a2, 0.f);
    }
    __syncthreads();

    if (t < 64) {
        float p = h2[t] * L3w[t];
#pragma unroll
        for (int off = 32; off > 0; off >>= 1) p += __shfl_down(p, off, 64);
        if (t == 0) out[g] = p + L3b[0];
    }
}

// ---------------- launch ----------------

static inline char* align16(char* p) {
    return (char*)(((uintptr_t)p + 15) & ~(uintptr_t)15);
}

extern "C" void kernel_launch(void* const* d_in, const int* in_sizes, int n_in,
                              void* d_out, int out_size, void* d_ws, size_t ws_size,
                              hipStream_t stream)
{
    const float* x     = (const float*)d_in[0];
    const int*   ei    = (const int*)d_in[1];
    const int*   batch = (const int*)d_in[2];
    const int N = in_sizes[0] / DH;
    const int E = in_sizes[1] / 2;
    const int G = out_size;
    const int* src = ei;
    const int* dst = ei + E;

    const float* W[3]  = {(const float*)d_in[3],  (const float*)d_in[9],  (const float*)d_in[15]};
    const float* cb[3] = {(const float*)d_in[4],  (const float*)d_in[10], (const float*)d_in[16]};
    const float* bg[3] = {(const float*)d_in[5],  (const float*)d_in[11], (const float*)d_in[17]};
    const float* bt[3] = {(const float*)d_in[6],  (const float*)d_in[12], (const float*)d_in[18]};
    const float* bm[3] = {(const float*)d_in[7],  (const float*)d_in[13], (const float*)d_in[19]};
    const float* bv[3] = {(const float*)d_in[8],  (const float*)d_in[14], (const float*)d_in[20]};
    const float* L1w = (const float*)d_in[21]; const float* L1b = (const float*)d_in[22];
    const float* L2w = (const float*)d_in[23]; const float* L2b = (const float*)d_in[24];
    const float* L3w = (const float*)d_in[25]; const float* L3b = (const float*)d_in[26];

    char* wsp = (char*)d_ws;
    size_t big = (size_t)N * DH * sizeof(float);
    float* P0 = (float*)wsp;  wsp += big;
    float* P1 = (float*)wsp;  wsp += big;
    float* P2 = (float*)wsp;  wsp += big;
    float* dinv   = (float*)wsp; wsp += (size_t)N * sizeof(float);
    int*   deg    = (int*)wsp;   wsp += (size_t)N * sizeof(int);
    int*   rowptr = (int*)wsp;   wsp = align16(wsp + (size_t)(N + 1) * sizeof(int));
    int*   cursor = (int*)wsp;   wsp += (size_t)N * sizeof(int);
    int*   csr_src= (int*)wsp;   wsp += (size_t)E * sizeof(int);
    int*   starts = (int*)wsp;   wsp = align16(wsp + (size_t)(G + 1) * sizeof(int));
    int*   bsum   = (int*)wsp;   wsp += 256 * sizeof(int);

    const int B = (N + 1023) / 1024;   // scan blocks (98 for N=100k, <=256 required)

    hipMemsetAsync(deg, 0, (size_t)N * sizeof(int), stream);
    k_count <<<(E + 255) / 256, 256, 0, stream>>>(dst, deg, E);
    k_dinv  <<<(N + 255) / 256, 256, 0, stream>>>(deg, dinv, N);
    k_bounds<<<(N + 255) / 256, 256, 0, stream>>>(batch, starts, N, G);
    k_scan1 <<<B, 256, 0, stream>>>(deg, rowptr, bsum, N);
    k_scan2 <<<1, 256, 0, stream>>>(bsum, B);
    k_scan3 <<<B, 256, 0, stream>>>(rowptr, bsum, N, E);
    hipMemcpyAsync(cursor, rowptr, (size_t)N * sizeof(int), hipMemcpyDeviceToDevice, stream);
    k_fill  <<<(E + 255) / 256, 256, 0, stream>>>(src, dst, cursor, csr_src, E);

    // layer plumbing:
    // L0: gemm(X=x,  hs=P0); gather(P0, prev=null, out=P1)
    // L1: gemm(X=P1, hs=P0); gather(P0, prev=P1,   out=P2)
    // L2: gemm(X=P2, hs=P0); gather(P0, prev=P2,   out=P1)
    const float* Xs[3]    = {x, P1, P2};
    const float* prevb[3] = {nullptr, P1, P2};
    float* xoutb[3]       = {P1, P2, P1};

    int gemmGrid = (N + 127) / 128;
    int gathGrid = (N * 64 + 255) / 256;

    for (int l = 0; l < 3; ++l) {
        k_gemm  <<<gemmGrid, 256, 0, stream>>>(Xs[l], W[l], dinv, P0, N);
        k_gather<<<gathGrid, 256, 0, stream>>>(P0, rowptr, csr_src, dinv,
                                               cb[l], bm[l], bv[l], bg[l], bt[l],
                                               prevb[l], xoutb[l], N);
    }

    k_pool_mlp<<<G, 128, 0, stream>>>(xoutb[2], starts, L1w, L1b, L2w, L2b, L3w, L3b,
                                      (float*)d_out);
}

// Round 3
// 866.132 us; speedup vs baseline: 5.3988x; 1.4317x over previous
//
#include <hip/hip_runtime.h>
#include <math.h>

#define DH 128
#define EPSB 1e-5f

typedef __attribute__((ext_vector_type(8))) short short8;
typedef __attribute__((ext_vector_type(4))) float f32x4;

static __device__ __forceinline__ unsigned short f2bf(float f) {
    unsigned u = __float_as_uint(f);
    u += 0x7fffu + ((u >> 16) & 1u);
    return (unsigned short)(u >> 16);
}
static __device__ __forceinline__ float bf2f(unsigned short h) {
    return __uint_as_float(((unsigned)h) << 16);
}

// ---------------- degree / dinv / graph boundaries ----------------

__global__ void k_count(const int* __restrict__ dst, int* __restrict__ deg, int E) {
    int i = blockIdx.x * blockDim.x + threadIdx.x;
    if (i < E) atomicAdd(&deg[dst[i]], 1);
}

__global__ void k_dinv(const int* __restrict__ deg, float* __restrict__ dinv, int N) {
    int i = blockIdx.x * blockDim.x + threadIdx.x;
    if (i < N) dinv[i] = rsqrtf((float)(deg[i] + 1));
}

__global__ void k_bounds(const int* __restrict__ batch, int* __restrict__ starts, int N, int G) {
    int i = blockIdx.x * blockDim.x + threadIdx.x;
    if (i < N) {
        int b = batch[i];
        if (i == 0) { starts[0] = 0; starts[G] = N; }
        else if (batch[i - 1] != b) starts[b] = i;
    }
}

// ---------------- exclusive scan of deg -> rowptr (3-pass) ----------------

__launch_bounds__(256)
__global__ void k_scan1(const int* __restrict__ deg, int* __restrict__ rowptr,
                        int* __restrict__ bsum, int N)
{
    __shared__ int wsum[4], woff[4];
    const int t = threadIdx.x;
    const int lane = t & 63, wid = t >> 6;
    const int base = blockIdx.x * 1024 + t * 4;

    int v[4], local = 0;
#pragma unroll
    for (int j = 0; j < 4; ++j) {
        v[j] = (base + j < N) ? deg[base + j] : 0;
        local += v[j];
    }
    int sc = local;
#pragma unroll
    for (int off = 1; off < 64; off <<= 1) {
        int n = __shfl_up(sc, off, 64);
        if (lane >= off) sc += n;
    }
    if (lane == 63) wsum[wid] = sc;
    __syncthreads();
    if (t == 0) {
        int r = 0;
#pragma unroll
        for (int i = 0; i < 4; ++i) { woff[i] = r; r += wsum[i]; }
        bsum[blockIdx.x] = r;
    }
    __syncthreads();
    int run = woff[wid] + sc - local;
#pragma unroll
    for (int j = 0; j < 4; ++j) {
        if (base + j < N) rowptr[base + j] = run;
        run += v[j];
    }
}

__global__ void k_scan2(int* __restrict__ bsum, int B) {
    __shared__ int s[256];
    int t = threadIdx.x;
    s[t] = (t < B) ? bsum[t] : 0;
    __syncthreads();
    for (int off = 1; off < 256; off <<= 1) {
        int v = (t >= off) ? s[t - off] : 0;
        __syncthreads();
        s[t] += v;
        __syncthreads();
    }
    if (t < B) bsum[t] = (t == 0) ? 0 : s[t - 1];
}

__launch_bounds__(256)
__global__ void k_scan3(int* __restrict__ rowptr, const int* __restrict__ bsum, int N, int E) {
    int t = threadIdx.x;
    int base = blockIdx.x * 1024 + t * 4;
    int off = bsum[blockIdx.x];
#pragma unroll
    for (int j = 0; j < 4; ++j)
        if (base + j < N) rowptr[base + j] += off;
    if (blockIdx.x == 0 && t == 0) rowptr[N] = E;
}

// ---------------- CSR fill ----------------

__global__ void k_fill(const int* __restrict__ src, const int* __restrict__ dst,
                       int* __restrict__ cursor, int* __restrict__ csr_src, int E)
{
    int e = blockIdx.x * blockDim.x + threadIdx.x;
    if (e < E) {
        int d = dst[e];
        int pos = atomicAdd(&cursor[d], 1);
        csr_src[pos] = src[e];
    }
}

// ---------------- W fragmentize + bf16 split ----------------
// 64 blocks x 64 threads per layer. Frag f = ((nh*2+p)*4+s)*4+nt.
// B-frag mapping (16x16x32 bf16): lane holds B[k = s*32 + quad*8 + j][n = nh*64+nt*16+(lane&15)]

__global__ void k_wfrag(const float* __restrict__ W, unsigned short* __restrict__ Wf) {
    int f = blockIdx.x;          // 0..63
    int lane = threadIdx.x;      // 0..63
    int nt = f & 3, s = (f >> 2) & 3, p = (f >> 4) & 1, nh = f >> 5;
    int n = nh * 64 + nt * 16 + (lane & 15);
    int kbase = s * 32 + (lane >> 4) * 8;
    unsigned short o[8];
#pragma unroll
    for (int j = 0; j < 8; ++j) {
        float w = W[(size_t)(kbase + j) * DH + n];
        unsigned short h = f2bf(w);
        o[j] = p ? f2bf(w - bf2f(h)) : h;
    }
    unsigned short* d = Wf + (size_t)f * 512 + lane * 8;
    *(ushort4*)d       = make_ushort4(o[0], o[1], o[2], o[3]);
    *(ushort4*)(d + 4) = make_ushort4(o[4], o[5], o[6], o[7]);
}

// ---------------- split fp32 -> bf16 hi/lo planes (layer-0 input) ----------------

__global__ void k_xsplit(const float4* __restrict__ X, ushort4* __restrict__ Xh,
                         ushort4* __restrict__ Xl, int n4) {
    int i = blockIdx.x * blockDim.x + threadIdx.x;
    if (i >= n4) return;
    float4 v = X[i];
    unsigned short h0 = f2bf(v.x), h1 = f2bf(v.y), h2 = f2bf(v.z), h3 = f2bf(v.w);
    Xh[i] = make_ushort4(h0, h1, h2, h3);
    Xl[i] = make_ushort4(f2bf(v.x - bf2f(h0)), f2bf(v.y - bf2f(h1)),
                         f2bf(v.z - bf2f(h2)), f2bf(v.w - bf2f(h3)));
}

// ---------------- MFMA GEMM: hs = (X @ W) * dinv[row], bf16x3 split ----------------
// block = 256 thr (4 waves), tile 128 rows x 128 cols; wave (mh,nh) owns 64x64.

__launch_bounds__(256, 2)
__global__ void k_gemm_mfma(const unsigned short* __restrict__ Xh,
                            const unsigned short* __restrict__ Xl,
                            const unsigned short* __restrict__ Wf,
                            const float* __restrict__ dinv,
                            float* __restrict__ hs, int N)
{
    __shared__ uint4 As4[2048];                 // 32 KB: 128 rows x 256 B
    unsigned short* As = (unsigned short*)As4;

    const int tid  = threadIdx.x;
    const int lane = tid & 63, wave = tid >> 6;
    const int mh = wave >> 1, nh = wave & 1;
    const int rowBase = blockIdx.x * 128;
    const int r15 = lane & 15, quad = lane >> 4;

    // W fragments: [plane][kstep][ntile], 4 VGPRs each (held for whole kernel)
    short8 wf[2][4][4];
#pragma unroll
    for (int p = 0; p < 2; ++p)
#pragma unroll
        for (int s = 0; s < 4; ++s)
#pragma unroll
            for (int nt = 0; nt < 4; ++nt)
                wf[p][s][nt] = *(const short8*)(Wf + ((((nh * 2 + p) * 4 + s) * 4 + nt) * 512) + lane * 8);

    f32x4 acc[4][4];
#pragma unroll
    for (int mt = 0; mt < 4; ++mt)
#pragma unroll
        for (int nt = 0; nt < 4; ++nt)
            acc[mt][nt] = (f32x4){0.f, 0.f, 0.f, 0.f};

    // ---- phase 1: hi plane, products Xh@Wh + Xh@Wl
    {
        const uint4* gp = (const uint4*)(Xh + (size_t)rowBase * DH);
#pragma unroll
        for (int it = 0; it < 8; ++it) As4[it * 256 + tid] = gp[it * 256 + tid];
    }
    __syncthreads();
#pragma unroll
    for (int s = 0; s < 4; ++s)
#pragma unroll
        for (int mt = 0; mt < 4; ++mt) {
            short8 a = *(const short8*)(As + (mh * 64 + mt * 16 + r15) * DH + s * 32 + quad * 8);
#pragma unroll
            for (int nt = 0; nt < 4; ++nt) {
                acc[mt][nt] = __builtin_amdgcn_mfma_f32_16x16x32_bf16(a, wf[0][s][nt], acc[mt][nt], 0, 0, 0);
                acc[mt][nt] = __builtin_amdgcn_mfma_f32_16x16x32_bf16(a, wf[1][s][nt], acc[mt][nt], 0, 0, 0);
            }
        }
    __syncthreads();
    // ---- phase 2: lo plane, product Xl@Wh
    {
        const uint4* gp = (const uint4*)(Xl + (size_t)rowBase * DH);
#pragma unroll
        for (int it = 0; it < 8; ++it) As4[it * 256 + tid] = gp[it * 256 + tid];
    }
    __syncthreads();
#pragma unroll
    for (int s = 0; s < 4; ++s)
#pragma unroll
        for (int mt = 0; mt < 4; ++mt) {
            short8 a = *(const short8*)(As + (mh * 64 + mt * 16 + r15) * DH + s * 32 + quad * 8);
#pragma unroll
            for (int nt = 0; nt < 4; ++nt)
                acc[mt][nt] = __builtin_amdgcn_mfma_f32_16x16x32_bf16(a, wf[0][s][nt], acc[mt][nt], 0, 0, 0);
        }

    // ---- epilogue: C/D layout col=lane&15, row=quad*4+reg
#pragma unroll
    for (int mt = 0; mt < 4; ++mt) {
        int rl = mh * 64 + mt * 16 + quad * 4;
#pragma unroll
        for (int reg = 0; reg < 4; ++reg) {
            int row = rowBase + rl + reg;
            if (row < N) {
                float sc = dinv[row];
#pragma unroll
                for (int nt = 0; nt < 4; ++nt)
                    hs[(size_t)row * DH + nh * 64 + nt * 16 + r15] = acc[mt][nt][reg] * sc;
            }
        }
    }
}

// ---------------- gather + fused post (+ bf16 split for next layer) ----------------

__launch_bounds__(256)
__global__ void k_gather(const float* __restrict__ hs, const int* __restrict__ rowptr,
                         const int* __restrict__ csr_src, const float* __restrict__ dinv,
                         const float* __restrict__ cb, const float* __restrict__ bm,
                         const float* __restrict__ bv, const float* __restrict__ bg,
                         const float* __restrict__ bb, const float* __restrict__ prev,
                         float* __restrict__ xout, unsigned short* __restrict__ xh,
                         unsigned short* __restrict__ xl, int N)
{
    const int w = (blockIdx.x * blockDim.x + threadIdx.x) >> 6;
    const int lane = threadIdx.x & 63;
    if (w >= N) return;
    const int f = lane * 2;
    const int e0 = rowptr[w], e1 = rowptr[w + 1];

    float2 acc = *(const float2*)(hs + (size_t)w * DH + f);   // self-loop

    for (int base = e0; base < e1; base += 64) {
        int cnt = e1 - base; if (cnt > 64) cnt = 64;
        int idx = (lane < cnt) ? csr_src[base + lane] : 0;
        int i = 0;
        for (; i + 4 <= cnt; i += 4) {
            int s0 = __shfl(idx, i, 64),     s1 = __shfl(idx, i + 1, 64);
            int s2 = __shfl(idx, i + 2, 64), s3 = __shfl(idx, i + 3, 64);
            float2 v0 = *(const float2*)(hs + (size_t)s0 * DH + f);
            float2 v1 = *(const float2*)(hs + (size_t)s1 * DH + f);
            float2 v2 = *(const float2*)(hs + (size_t)s2 * DH + f);
            float2 v3 = *(const float2*)(hs + (size_t)s3 * DH + f);
            acc.x += (v0.x + v1.x) + (v2.x + v3.x);
            acc.y += (v0.y + v1.y) + (v2.y + v3.y);
        }
        for (; i < cnt; ++i) {
            int s = __shfl(idx, i, 64);
            float2 v = *(const float2*)(hs + (size_t)s * DH + f);
            acc.x += v.x; acc.y += v.y;
        }
    }

    const float sc = dinv[w];
    float o0 = acc.x * sc + cb[f];
    float o1 = acc.y * sc + cb[f + 1];
    o0 = (o0 - bm[f])     * rsqrtf(bv[f]     + EPSB) * bg[f]     + bb[f];
    o1 = (o1 - bm[f + 1]) * rsqrtf(bv[f + 1] + EPSB) * bg[f + 1] + bb[f + 1];
    o0 = fmaxf(o0, 0.f);
    o1 = fmaxf(o1, 0.f);
    if (prev) {
        const float2 p = *(const float2*)(prev + (size_t)w * DH + f);
        o0 += p.x; o1 += p.y;
    }
    *(float2*)(xout + (size_t)w * DH + f) = make_float2(o0, o1);
    if (xh) {
        unsigned short h0 = f2bf(o0), h1 = f2bf(o1);
        *(ushort2*)(xh + (size_t)w * DH + f) = make_ushort2(h0, h1);
        *(ushort2*)(xl + (size_t)w * DH + f) =
            make_ushort2(f2bf(o0 - bf2f(h0)), f2bf(o1 - bf2f(h1)));
    }
}

// ---------------- fused pool (mean+max) + 3-layer MLP head ----------------

__launch_bounds__(128)
__global__ void k_pool_mlp(const float* __restrict__ x, const int* __restrict__ starts,
                           const float* __restrict__ L1w, const float* __restrict__ L1b,
                           const float* __restrict__ L2w, const float* __restrict__ L2b,
                           const float* __restrict__ L3w, const float* __restrict__ L3b,
                           float* __restrict__ out)
{
    int g = blockIdx.x, t = threadIdx.x;
    int s0 = starts[g], s1 = starts[g + 1];
    float sum = 0.f, mx = -INFINITY;
    for (int i = s0; i < s1; ++i) {
        float v = x[(size_t)i * DH + t];
        sum += v;
        mx = fmaxf(mx, v);
    }
    __shared__ float h[256];
    h[t] = sum / (float)(s1 - s0);
    h[128 + t] = mx;
    __syncthreads();

    float a = L1b[t];
    for (int k = 0; k < 256; ++k) a += h[k] * L1w[k * DH + t];
    __shared__ float h1[128];
    h1[t] = fmaxf(a, 0.f);
    __syncthreads();

    __shared__ float h2[64];
    if (t < 64) {
        float a2 = L2b[t];
        for (int k = 0; k < 128; ++k) a2 += h1[k] * L2w[k * 64 + t];
        h2[t] = fmaxf(a2, 0.f);
    }
    __syncthreads();

    if (t < 64) {
        float p = h2[t] * L3w[t];
#pragma unroll
        for (int off = 32; off > 0; off >>= 1) p += __shfl_down(p, off, 64);
        if (t == 0) out[g] = p + L3b[0];
    }
}

// ---------------- launch ----------------

static inline char* align16(char* p) {
    return (char*)(((uintptr_t)p + 15) & ~(uintptr_t)15);
}

extern "C" void kernel_launch(void* const* d_in, const int* in_sizes, int n_in,
                              void* d_out, int out_size, void* d_ws, size_t ws_size,
                              hipStream_t stream)
{
    const float* x     = (const float*)d_in[0];
    const int*   ei    = (const int*)d_in[1];
    const int*   batch = (const int*)d_in[2];
    const int N = in_sizes[0] / DH;
    const int E = in_sizes[1] / 2;
    const int G = out_size;
    const int* src = ei;
    const int* dst = ei + E;

    const float* W[3]  = {(const float*)d_in[3],  (const float*)d_in[9],  (const float*)d_in[15]};
    const float* cb[3] = {(const float*)d_in[4],  (const float*)d_in[10], (const float*)d_in[16]};
    const float* bg[3] = {(const float*)d_in[5],  (const float*)d_in[11], (const float*)d_in[17]};
    const float* bt[3] = {(const float*)d_in[6],  (const float*)d_in[12], (const float*)d_in[18]};
    const float* bm[3] = {(const float*)d_in[7],  (const float*)d_in[13], (const float*)d_in[19]};
    const float* bv[3] = {(const float*)d_in[8],  (const float*)d_in[14], (const float*)d_in[20]};
    const float* L1w = (const float*)d_in[21]; const float* L1b = (const float*)d_in[22];
    const float* L2w = (const float*)d_in[23]; const float* L2b = (const float*)d_in[24];
    const float* L3w = (const float*)d_in[25]; const float* L3b = (const float*)d_in[26];

    char* wsp = (char*)d_ws;
    size_t planeB = (size_t)N * DH * sizeof(unsigned short);   // 25.6 MB
    size_t big    = (size_t)N * DH * sizeof(float);            // 51.2 MB
    unsigned short* Xh = (unsigned short*)wsp; wsp += planeB;
    unsigned short* Xl = (unsigned short*)wsp; wsp += planeB;
    float* P0 = (float*)wsp;  wsp += big;    // hs
    float* P1 = (float*)wsp;  wsp += big;
    float* P2 = (float*)wsp;  wsp += big;
    unsigned short* Wfrag = (unsigned short*)wsp; wsp += 3 * 65536;   // 64 KB/layer
    float* dinv   = (float*)wsp; wsp += (size_t)N * sizeof(float);
    int*   deg    = (int*)wsp;   wsp += (size_t)N * sizeof(int);
    int*   rowptr = (int*)wsp;   wsp = align16(wsp + (size_t)(N + 1) * sizeof(int));
    int*   cursor = (int*)wsp;   wsp += (size_t)N * sizeof(int);
    int*   csr_src= (int*)wsp;   wsp += (size_t)E * sizeof(int);
    int*   starts = (int*)wsp;   wsp = align16(wsp + (size_t)(G + 1) * sizeof(int));
    int*   bsum   = (int*)wsp;   wsp += 256 * sizeof(int);

    const int B = (N + 1023) / 1024;

    hipMemsetAsync(deg, 0, (size_t)N * sizeof(int), stream);
    k_count <<<(E + 255) / 256, 256, 0, stream>>>(dst, deg, E);
    k_dinv  <<<(N + 255) / 256, 256, 0, stream>>>(deg, dinv, N);
    k_bounds<<<(N + 255) / 256, 256, 0, stream>>>(batch, starts, N, G);
    k_scan1 <<<B, 256, 0, stream>>>(deg, rowptr, bsum, N);
    k_scan2 <<<1, 256, 0, stream>>>(bsum, B);
    k_scan3 <<<B, 256, 0, stream>>>(rowptr, bsum, N, E);
    hipMemcpyAsync(cursor, rowptr, (size_t)N * sizeof(int), hipMemcpyDeviceToDevice, stream);
    k_fill  <<<(E + 255) / 256, 256, 0, stream>>>(src, dst, cursor, csr_src, E);

    for (int l = 0; l < 3; ++l)
        k_wfrag<<<64, 64, 0, stream>>>(W[l], Wfrag + (size_t)l * 32768);

    k_xsplit<<<(N * 32 + 255) / 256, 256, 0, stream>>>((const float4*)x,
                                                       (ushort4*)Xh, (ushort4*)Xl, N * 32);

    // L0: gemm(Xhl -> hs=P0); gather(P0, prev=null, out=P1, split->Xhl)
    // L1: gemm(Xhl -> hs=P0); gather(P0, prev=P1,   out=P2, split->Xhl)
    // L2: gemm(Xhl -> hs=P0); gather(P0, prev=P2,   out=P1, no split)
    const float* prevb[3] = {nullptr, P1, P2};
    float* xoutb[3]       = {P1, P2, P1};

    int gemmGrid = (N + 127) / 128;
    int gathGrid = (N * 64 + 255) / 256;

    for (int l = 0; l < 3; ++l) {
        k_gemm_mfma<<<gemmGrid, 256, 0, stream>>>(Xh, Xl, Wfrag + (size_t)l * 32768,
                                                  dinv, P0, N);
        unsigned short* xho = (l < 2) ? Xh : nullptr;
        unsigned short* xlo = (l < 2) ? Xl : nullptr;
        k_gather<<<gathGrid, 256, 0, stream>>>(P0, rowptr, csr_src, dinv,
                                               cb[l], bm[l], bv[l], bg[l], bt[l],
                                               prevb[l], xoutb[l], xho, xlo, N);
    }

    k_pool_mlp<<<G, 128, 0, stream>>>(xoutb[2], starts, L1w, L1b, L2w, L2b, L3w, L3b,
                                      (float*)d_out);
}

// Round 4
// 591.380 us; speedup vs baseline: 7.9071x; 1.4646x over previous
//
#include <hip/hip_runtime.h>
#include <math.h>

#define DH 128
#define EPSB 1e-5f
#define MAXB 832     // max buckets (N <= 106496)
#define BCAP 3072    // bucket capacity (mean ~2046, +22 sigma)

typedef __attribute__((ext_vector_type(8))) short short8;
typedef __attribute__((ext_vector_type(4))) float f32x4;

static __device__ __forceinline__ unsigned short f2bf(float f) {
    unsigned u = __float_as_uint(f);
    u += 0x7fffu + ((u >> 16) & 1u);
    return (unsigned short)(u >> 16);
}
static __device__ __forceinline__ float bf2f(unsigned short h) {
    return __uint_as_float(((unsigned)h) << 16);
}

// ---------------- dinv / graph boundaries ----------------

__global__ void k_dinv(const int* __restrict__ deg, float* __restrict__ dinv, int N) {
    int i = blockIdx.x * blockDim.x + threadIdx.x;
    if (i < N) dinv[i] = rsqrtf((float)(deg[i] + 1));
}

__global__ void k_bounds(const int* __restrict__ batch, int* __restrict__ starts, int N, int G) {
    int i = blockIdx.x * blockDim.x + threadIdx.x;
    if (i < N) {
        int b = batch[i];
        if (i == 0) { starts[0] = 0; starts[G] = N; }
        else if (batch[i - 1] != b) starts[b] = i;
    }
}

// ---------------- bucketed CSR build ----------------
// pass A: partition edges into buckets of 128 dsts; contiguous per-block reservations

__launch_bounds__(256)
__global__ void k_bucketA(const int* __restrict__ src, const int* __restrict__ dst,
                          int* __restrict__ gcur, int2* __restrict__ bbuf,
                          int E, int NB, int chunk)
{
    __shared__ int cnt[MAXB];
    __shared__ int base[MAXB];
    const int t = threadIdx.x;
    for (int i = t; i < NB; i += 256) cnt[i] = 0;
    __syncthreads();
    const int e0 = blockIdx.x * chunk;
    const int e1 = min(E, e0 + chunk);
    for (int e = e0 + t; e < e1; e += 256)
        atomicAdd(&cnt[dst[e] >> 7], 1);
    __syncthreads();
    for (int i = t; i < NB; i += 256) {
        int c = cnt[i];
        base[i] = (c > 0) ? atomicAdd(&gcur[i], c) : 0;
        cnt[i] = 0;
    }
    __syncthreads();
    for (int e = e0 + t; e < e1; e += 256) {
        int d = dst[e];
        int b = d >> 7;
        int o = base[b] + atomicAdd(&cnt[b], 1);
        if (o < BCAP) bbuf[(size_t)b * BCAP + o] = make_int2(src[e], d);
    }
}

// pass B1: per-bucket degree count, coalesced deg write
__launch_bounds__(256)
__global__ void k_bdeg(const int* __restrict__ gcur, const int2* __restrict__ bbuf,
                       int* __restrict__ deg, int N)
{
    __shared__ int dcnt[128];
    const int b = blockIdx.x, t = threadIdx.x;
    if (t < 128) dcnt[t] = 0;
    __syncthreads();
    int c = gcur[b]; if (c > BCAP) c = BCAP;
    const int2* p = bbuf + (size_t)b * BCAP;
    for (int i = t; i < c; i += 256) atomicAdd(&dcnt[p[i].y & 127], 1);
    __syncthreads();
    int d = b * 128 + t;
    if (t < 128 && d < N) deg[d] = dcnt[t];
}

// pass B2: scatter srcs into csr within the bucket's contiguous window
__launch_bounds__(256)
__global__ void k_bscatter(const int* __restrict__ gcur, const int2* __restrict__ bbuf,
                           const int* __restrict__ rowptr, int* __restrict__ csr_src, int N)
{
    __shared__ int rp[128];
    __shared__ int off[128];
    const int b = blockIdx.x, t = threadIdx.x;
    if (t < 128) {
        int d = b * 128 + t;
        off[t] = 0;
        rp[t] = (d < N) ? rowptr[d] : 0;
    }
    __syncthreads();
    int c = gcur[b]; if (c > BCAP) c = BCAP;
    const int2* p = bbuf + (size_t)b * BCAP;
    for (int i = t; i < c; i += 256) {
        int2 e = p[i];
        int dl = e.y & 127;
        int o = atomicAdd(&off[dl], 1);
        csr_src[rp[dl] + o] = e.x;
    }
}

// ---------------- exclusive scan of deg -> rowptr (3-pass) ----------------

__launch_bounds__(256)
__global__ void k_scan1(const int* __restrict__ deg, int* __restrict__ rowptr,
                        int* __restrict__ bsum, int N)
{
    __shared__ int wsum[4], woff[4];
    const int t = threadIdx.x;
    const int lane = t & 63, wid = t >> 6;
    const int base = blockIdx.x * 1024 + t * 4;

    int v[4], local = 0;
#pragma unroll
    for (int j = 0; j < 4; ++j) {
        v[j] = (base + j < N) ? deg[base + j] : 0;
        local += v[j];
    }
    int sc = local;
#pragma unroll
    for (int off = 1; off < 64; off <<= 1) {
        int n = __shfl_up(sc, off, 64);
        if (lane >= off) sc += n;
    }
    if (lane == 63) wsum[wid] = sc;
    __syncthreads();
    if (t == 0) {
        int r = 0;
#pragma unroll
        for (int i = 0; i < 4; ++i) { woff[i] = r; r += wsum[i]; }
        bsum[blockIdx.x] = r;
    }
    __syncthreads();
    int run = woff[wid] + sc - local;
#pragma unroll
    for (int j = 0; j < 4; ++j) {
        if (base + j < N) rowptr[base + j] = run;
        run += v[j];
    }
}

__global__ void k_scan2(int* __restrict__ bsum, int B) {
    __shared__ int s[256];
    int t = threadIdx.x;
    s[t] = (t < B) ? bsum[t] : 0;
    __syncthreads();
    for (int off = 1; off < 256; off <<= 1) {
        int v = (t >= off) ? s[t - off] : 0;
        __syncthreads();
        s[t] += v;
        __syncthreads();
    }
    if (t < B) bsum[t] = (t == 0) ? 0 : s[t - 1];
}

__launch_bounds__(256)
__global__ void k_scan3(int* __restrict__ rowptr, const int* __restrict__ bsum, int N, int E) {
    int t = threadIdx.x;
    int base = blockIdx.x * 1024 + t * 4;
    int off = bsum[blockIdx.x];
#pragma unroll
    for (int j = 0; j < 4; ++j)
        if (base + j < N) rowptr[base + j] += off;
    if (blockIdx.x == 0 && t == 0) rowptr[N] = E;
}

// ---------------- W fragmentize + bf16 split ----------------
// Frag f = ((nh*2+p)*4+s)*4+nt; lane holds B[k=s*32+quad*8+j][n=nh*64+nt*16+(lane&15)]

__global__ void k_wfrag(const float* __restrict__ W, unsigned short* __restrict__ Wf) {
    int f = blockIdx.x;          // 0..63
    int lane = threadIdx.x;      // 0..63
    int nt = f & 3, s = (f >> 2) & 3, p = (f >> 4) & 1, nh = f >> 5;
    int n = nh * 64 + nt * 16 + (lane & 15);
    int kbase = s * 32 + (lane >> 4) * 8;
    unsigned short o[8];
#pragma unroll
    for (int j = 0; j < 8; ++j) {
        float w = W[(size_t)(kbase + j) * DH + n];
        unsigned short h = f2bf(w);
        o[j] = p ? f2bf(w - bf2f(h)) : h;
    }
    unsigned short* d = Wf + (size_t)f * 512 + lane * 8;
    *(ushort4*)d       = make_ushort4(o[0], o[1], o[2], o[3]);
    *(ushort4*)(d + 4) = make_ushort4(o[4], o[5], o[6], o[7]);
}

// ---------------- MFMA GEMM: hs_bf16 = bf16((X @ W) * dinv[row]) ----------------
// fp32 X staged in LDS; hi/lo bf16 split in-register; bf16x3 products.
// block = 256 thr (4 waves), tile 64 rows x 128 cols; wave (mh,nh) owns 32x64.

__launch_bounds__(256)
__global__ void k_gemm_mfma(const float* __restrict__ X,
                            const unsigned short* __restrict__ Wf,
                            const float* __restrict__ dinv,
                            unsigned short* __restrict__ hs, int N)
{
    __shared__ float As[64 * DH];   // 32 KB

    const int tid  = threadIdx.x;
    const int lane = tid & 63, wave = tid >> 6;
    const int mh = wave >> 1, nh = wave & 1;
    const int rowBase = blockIdx.x * 64;
    const int r15 = lane & 15, quad = lane >> 4;

    {
        const float4* gp = (const float4*)(X + (size_t)rowBase * DH);
        float4* sp = (float4*)As;
#pragma unroll
        for (int it = 0; it < 8; ++it) {
            int idx = it * 256 + tid;
            int grow = idx >> 5;                     // 32 float4 per row
            float4 v = make_float4(0.f, 0.f, 0.f, 0.f);
            if (rowBase + grow < N) v = gp[idx];
            sp[idx] = v;
        }
    }
    __syncthreads();

    f32x4 acc[2][4];
#pragma unroll
    for (int mt = 0; mt < 2; ++mt)
#pragma unroll
        for (int nt = 0; nt < 4; ++nt)
            acc[mt][nt] = (f32x4){0.f, 0.f, 0.f, 0.f};

#pragma unroll
    for (int s = 0; s < 4; ++s) {
        short8 wfh[4], wfl[4];
#pragma unroll
        for (int nt = 0; nt < 4; ++nt) {
            wfh[nt] = *(const short8*)(Wf + ((((nh * 2 + 0) * 4 + s) * 4 + nt) * 512) + lane * 8);
            wfl[nt] = *(const short8*)(Wf + ((((nh * 2 + 1) * 4 + s) * 4 + nt) * 512) + lane * 8);
        }
#pragma unroll
        for (int mt = 0; mt < 2; ++mt) {
            const float* ap = As + (mh * 32 + mt * 16 + r15) * DH + s * 32 + quad * 8;
            short8 ah, al;
#pragma unroll
            for (int j = 0; j < 8; ++j) {
                float v = ap[j];
                unsigned short h = f2bf(v);
                ah[j] = (short)h;
                al[j] = (short)f2bf(v - bf2f(h));
            }
#pragma unroll
            for (int nt = 0; nt < 4; ++nt) {
                acc[mt][nt] = __builtin_amdgcn_mfma_f32_16x16x32_bf16(ah, wfh[nt], acc[mt][nt], 0, 0, 0);
                acc[mt][nt] = __builtin_amdgcn_mfma_f32_16x16x32_bf16(ah, wfl[nt], acc[mt][nt], 0, 0, 0);
                acc[mt][nt] = __builtin_amdgcn_mfma_f32_16x16x32_bf16(al, wfh[nt], acc[mt][nt], 0, 0, 0);
            }
        }
    }

    // epilogue: C/D layout col=lane&15, row=quad*4+reg
#pragma unroll
    for (int mt = 0; mt < 2; ++mt) {
        int rl = mh * 32 + mt * 16 + quad * 4;
#pragma unroll
        for (int reg = 0; reg < 4; ++reg) {
            int row = rowBase + rl + reg;
            if (row < N) {
                float sc = dinv[row];
#pragma unroll
                for (int nt = 0; nt < 4; ++nt)
                    hs[(size_t)row * DH + nh * 64 + nt * 16 + r15] = f2bf(acc[mt][nt][reg] * sc);
            }
        }
    }
}

// ---------------- gather (bf16 hs) + fused post ----------------

__launch_bounds__(256)
__global__ void k_gather(const unsigned short* __restrict__ hs, const int* __restrict__ rowptr,
                         const int* __restrict__ csr_src, const float* __restrict__ dinv,
                         const float* __restrict__ cb, const float* __restrict__ bm,
                         const float* __restrict__ bv, const float* __restrict__ bg,
                         const float* __restrict__ bb, const float* __restrict__ prev,
                         float* __restrict__ xout, int N)
{
    const int w = (blockIdx.x * blockDim.x + threadIdx.x) >> 6;
    const int lane = threadIdx.x & 63;
    if (w >= N) return;
    const int f = lane * 2;
    const int e0 = rowptr[w], e1 = rowptr[w + 1];

    ushort2 su = *(const ushort2*)(hs + (size_t)w * DH + f);    // self-loop
    float2 acc = make_float2(bf2f(su.x), bf2f(su.y));

    for (int base = e0; base < e1; base += 64) {
        int cnt = e1 - base; if (cnt > 64) cnt = 64;
        int idx = (lane < cnt) ? csr_src[base + lane] : 0;
        int i = 0;
        for (; i + 4 <= cnt; i += 4) {
            int s0 = __shfl(idx, i, 64),     s1 = __shfl(idx, i + 1, 64);
            int s2 = __shfl(idx, i + 2, 64), s3 = __shfl(idx, i + 3, 64);
            ushort2 v0 = *(const ushort2*)(hs + (size_t)s0 * DH + f);
            ushort2 v1 = *(const ushort2*)(hs + (size_t)s1 * DH + f);
            ushort2 v2 = *(const ushort2*)(hs + (size_t)s2 * DH + f);
            ushort2 v3 = *(const ushort2*)(hs + (size_t)s3 * DH + f);
            acc.x += (bf2f(v0.x) + bf2f(v1.x)) + (bf2f(v2.x) + bf2f(v3.x));
            acc.y += (bf2f(v0.y) + bf2f(v1.y)) + (bf2f(v2.y) + bf2f(v3.y));
        }
        for (; i < cnt; ++i) {
            int s = __shfl(idx, i, 64);
            ushort2 v = *(const ushort2*)(hs + (size_t)s * DH + f);
            acc.x += bf2f(v.x); acc.y += bf2f(v.y);
        }
    }

    const float sc = dinv[w];
    float o0 = acc.x * sc + cb[f];
    float o1 = acc.y * sc + cb[f + 1];
    o0 = (o0 - bm[f])     * rsqrtf(bv[f]     + EPSB) * bg[f]     + bb[f];
    o1 = (o1 - bm[f + 1]) * rsqrtf(bv[f + 1] + EPSB) * bg[f + 1] + bb[f + 1];
    o0 = fmaxf(o0, 0.f);
    o1 = fmaxf(o1, 0.f);
    if (prev) {
        const float2 p = *(const float2*)(prev + (size_t)w * DH + f);
        o0 += p.x; o1 += p.y;
    }
    *(float2*)(xout + (size_t)w * DH + f) = make_float2(o0, o1);
}

// ---------------- fused pool (mean+max) + 3-layer MLP head ----------------

__launch_bounds__(128)
__global__ void k_pool_mlp(const float* __restrict__ x, const int* __restrict__ starts,
                           const float* __restrict__ L1w, const float* __restrict__ L1b,
                           const float* __restrict__ L2w, const float* __restrict__ L2b,
                           const float* __restrict__ L3w, const float* __restrict__ L3b,
                           float* __restrict__ out)
{
    int g = blockIdx.x, t = threadIdx.x;
    int s0 = starts[g], s1 = starts[g + 1];
    float sum = 0.f, mx = -INFINITY;
    for (int i = s0; i < s1; ++i) {
        float v = x[(size_t)i * DH + t];
        sum += v;
        mx = fmaxf(mx, v);
    }
    __shared__ float h[256];
    h[t] = sum / (float)(s1 - s0);
    h[128 + t] = mx;
    __syncthreads();

    float a = L1b[t];
    for (int k = 0; k < 256; ++k) a += h[k] * L1w[k * DH + t];
    __shared__ float h1[128];
    h1[t] = fmaxf(a, 0.f);
    __syncthreads();

    __shared__ float h2[64];
    if (t < 64) {
        float a2 = L2b[t];
        for (int k = 0; k < 128; ++k) a2 += h1[k] * L2w[k * 64 + t];
        h2[t] = fmaxf(a2, 0.f);
    }
    __syncthreads();

    if (t < 64) {
        float p = h2[t] * L3w[t];
#pragma unroll
        for (int off = 32; off > 0; off >>= 1) p += __shfl_down(p, off, 64);
        if (t == 0) out[g] = p + L3b[0];
    }
}

// ---------------- launch ----------------

static inline char* align16(char* p) {
    return (char*)(((uintptr_t)p + 15) & ~(uintptr_t)15);
}

extern "C" void kernel_launch(void* const* d_in, const int* in_sizes, int n_in,
                              void* d_out, int out_size, void* d_ws, size_t ws_size,
                              hipStream_t stream)
{
    const float* x     = (const float*)d_in[0];
    const int*   ei    = (const int*)d_in[1];
    const int*   batch = (const int*)d_in[2];
    const int N = in_sizes[0] / DH;
    const int E = in_sizes[1] / 2;
    const int G = out_size;
    const int* src = ei;
    const int* dst = ei + E;

    const float* W[3]  = {(const float*)d_in[3],  (const float*)d_in[9],  (const float*)d_in[15]};
    const float* cb[3] = {(const float*)d_in[4],  (const float*)d_in[10], (const float*)d_in[16]};
    const float* bg[3] = {(const float*)d_in[5],  (const float*)d_in[11], (const float*)d_in[17]};
    const float* bt[3] = {(const float*)d_in[6],  (const float*)d_in[12], (const float*)d_in[18]};
    const float* bm[3] = {(const float*)d_in[7],  (const float*)d_in[13], (const float*)d_in[19]};
    const float* bv[3] = {(const float*)d_in[8],  (const float*)d_in[14], (const float*)d_in[20]};
    const float* L1w = (const float*)d_in[21]; const float* L1b = (const float*)d_in[22];
    const float* L2w = (const float*)d_in[23]; const float* L2b = (const float*)d_in[24];
    const float* L3w = (const float*)d_in[25]; const float* L3b = (const float*)d_in[26];

    char* wsp = (char*)d_ws;
    size_t big = (size_t)N * DH * sizeof(float);                  // 51.2 MB
    unsigned short* HS = (unsigned short*)wsp; wsp += (size_t)N * DH * sizeof(unsigned short);
    float* P1 = (float*)wsp;  wsp += big;
    float* P2 = (float*)wsp;  wsp += big;
    unsigned short* Wfrag = (unsigned short*)wsp; wsp += 3 * 65536;
    float* dinv   = (float*)wsp; wsp += (size_t)N * sizeof(float);
    int*   deg    = (int*)wsp;   wsp += (size_t)N * sizeof(int);
    int*   rowptr = (int*)wsp;   wsp = align16(wsp + (size_t)(N + 1) * sizeof(int));
    int*   csr_src= (int*)wsp;   wsp += (size_t)E * sizeof(int);
    int*   starts = (int*)wsp;   wsp = align16(wsp + (size_t)(G + 1) * sizeof(int));
    int*   bsum   = (int*)wsp;   wsp += 256 * sizeof(int);
    int*   gcur   = (int*)wsp;   wsp = align16(wsp + (size_t)MAXB * sizeof(int));
    int2*  bbuf   = (int2*)wsp;  wsp += (size_t)MAXB * BCAP * sizeof(int2);   // 20.4 MB

    const int NB = (N + 127) >> 7;          // 782 buckets
    const int B  = (N + 1023) / 1024;       // scan blocks
    const int nblkA = 128;
    const int chunk = (E + nblkA - 1) / nblkA;

    hipMemsetAsync(gcur, 0, (size_t)NB * sizeof(int), stream);
    k_bucketA <<<nblkA, 256, 0, stream>>>(src, dst, gcur, bbuf, E, NB, chunk);
    k_bdeg    <<<NB, 256, 0, stream>>>(gcur, bbuf, deg, N);
    k_dinv    <<<(N + 255) / 256, 256, 0, stream>>>(deg, dinv, N);
    k_bounds  <<<(N + 255) / 256, 256, 0, stream>>>(batch, starts, N, G);
    k_scan1   <<<B, 256, 0, stream>>>(deg, rowptr, bsum, N);
    k_scan2   <<<1, 256, 0, stream>>>(bsum, B);
    k_scan3   <<<B, 256, 0, stream>>>(rowptr, bsum, N, E);
    k_bscatter<<<NB, 256, 0, stream>>>(gcur, bbuf, rowptr, csr_src, N);

    for (int l = 0; l < 3; ++l)
        k_wfrag<<<64, 64, 0, stream>>>(W[l], Wfrag + (size_t)l * 32768);

    // L0: gemm(x  -> HS); gather(HS, prev=null, out=P1)
    // L1: gemm(P1 -> HS); gather(HS, prev=P1,   out=P2)
    // L2: gemm(P2 -> HS); gather(HS, prev=P2,   out=P1)
    const float* Xs[3]    = {x, P1, P2};
    const float* prevb[3] = {nullptr, P1, P2};
    float* xoutb[3]       = {P1, P2, P1};

    int gemmGrid = (N + 63) / 64;
    int gathGrid = (N * 64 + 255) / 256;

    for (int l = 0; l < 3; ++l) {
        k_gemm_mfma<<<gemmGrid, 256, 0, stream>>>(Xs[l], Wfrag + (size_t)l * 32768,
                                                  dinv, HS, N);
        k_gather<<<gathGrid, 256, 0, stream>>>(HS, rowptr, csr_src, dinv,
                                               cb[l], bm[l], bv[l], bg[l], bt[l],
                                               prevb[l], xoutb[l], N);
    }

    k_pool_mlp<<<G, 128, 0, stream>>>(xoutb[2], starts, L1w, L1b, L2w, L2b, L3w, L3b,
                                      (float*)d_out);
}

// Round 5
// 521.578 us; speedup vs baseline: 8.9653x; 1.1338x over previous
//
#include <hip/hip_runtime.h>
#include <math.h>

#define DH 128
#define EPSB 1e-5f
#define MAXB 832     // max buckets (N <= 106496)
#define BCAP 3072    // bucket capacity (mean ~2046 at E/N=16)

typedef __attribute__((ext_vector_type(8))) short short8;
typedef __attribute__((ext_vector_type(4))) float f32x4;

static __device__ __forceinline__ unsigned short f2bf(float f) {
    unsigned u = __float_as_uint(f);
    u += 0x7fffu + ((u >> 16) & 1u);
    return (unsigned short)(u >> 16);
}
static __device__ __forceinline__ float bf2f(unsigned short h) {
    return __uint_as_float(((unsigned)h) << 16);
}

// ---------------- graph boundaries ----------------

__global__ void k_bounds(const int* __restrict__ batch, int* __restrict__ starts, int N, int G) {
    int i = blockIdx.x * blockDim.x + threadIdx.x;
    if (i < N) {
        int b = batch[i];
        if (i == 0) { starts[0] = 0; starts[G] = N; }
        else if (batch[i - 1] != b) starts[b] = i;
    }
}

// ---------------- bucketed CSR build ----------------
// pass A: partition edges into buckets of 128 dsts; packed entry (src<<7)|dlocal

__launch_bounds__(256)
__global__ void k_bucketA(const int* __restrict__ src, const int* __restrict__ dst,
                          int* __restrict__ gcur, int* __restrict__ bbuf,
                          int E, int NB, int chunk)
{
    __shared__ int cnt[MAXB];
    __shared__ int base[MAXB];
    const int t = threadIdx.x;
    for (int i = t; i < NB; i += 256) cnt[i] = 0;
    __syncthreads();
    const int e0 = blockIdx.x * chunk;
    const int e1 = min(E, e0 + chunk);
    for (int e = e0 + t; e < e1; e += 256)
        atomicAdd(&cnt[dst[e] >> 7], 1);
    __syncthreads();
    for (int i = t; i < NB; i += 256) {
        int c = cnt[i];
        base[i] = (c > 0) ? atomicAdd(&gcur[i], c) : 0;
        cnt[i] = 0;
    }
    __syncthreads();
    for (int e = e0 + t; e < e1; e += 256) {
        int d = dst[e];
        int b = d >> 7;
        int o = base[b] + atomicAdd(&cnt[b], 1);
        if (o < BCAP) bbuf[(size_t)b * BCAP + o] = (src[e] << 7) | (d & 127);
    }
}

// pass B: single-block exclusive scan of bucket counts -> bucket_base; rowptr[N]=E
__launch_bounds__(1024)
__global__ void k_bgscan(const int* __restrict__ gcur, int* __restrict__ bbase,
                         int* __restrict__ rowptr, int NB, int N, int E)
{
    __shared__ int s[1024];
    int t = threadIdx.x;
    int v = (t < NB) ? min(gcur[t], BCAP) : 0;
    s[t] = v;
    __syncthreads();
    for (int off = 1; off < 1024; off <<= 1) {
        int u = (t >= off) ? s[t - off] : 0;
        __syncthreads();
        s[t] += u;
        __syncthreads();
    }
    if (t < NB) bbase[t] = s[t] - v;   // exclusive
    if (t == 0) rowptr[N] = E;
}

// pass C: per-bucket: deg count, dinv, rowptr, csr scatter (bucket staged in LDS)
__launch_bounds__(256)
__global__ void k_bfinal(const int* __restrict__ gcur, const int* __restrict__ bbase,
                         const int* __restrict__ bbuf, int* __restrict__ rowptr,
                         float* __restrict__ dinv, int* __restrict__ csr_src, int N)
{
    __shared__ int ebuf[BCAP];
    __shared__ int dcnt[128];
    __shared__ int sp[128];
    const int b = blockIdx.x, t = threadIdx.x;
    const int c = min(gcur[b], BCAP);
    const int base = bbase[b];
    const int* p = bbuf + (size_t)b * BCAP;
    for (int i = t; i < c; i += 256) ebuf[i] = p[i];
    if (t < 128) dcnt[t] = 0;
    __syncthreads();
    for (int i = t; i < c; i += 256) atomicAdd(&dcnt[ebuf[i] & 127], 1);
    __syncthreads();
    if (t < 128) sp[t] = dcnt[t];
    __syncthreads();
    // inclusive scan of 128
    for (int off = 1; off < 128; off <<= 1) {
        int u = (t < 128 && t >= off) ? sp[t - off] : 0;
        __syncthreads();
        if (t < 128) sp[t] += u;
        __syncthreads();
    }
    if (t < 128) {
        sp[t] -= dcnt[t];                 // exclusive
        int d = b * 128 + t;
        if (d < N) {
            rowptr[d] = base + sp[t];
            dinv[d] = rsqrtf((float)(dcnt[t] + 1));
        }
        dcnt[t] = 0;                      // reuse as cursor
    }
    __syncthreads();
    for (int i = t; i < c; i += 256) {
        int e = ebuf[i];
        int dl = e & 127;
        int o = atomicAdd(&dcnt[dl], 1);
        csr_src[base + sp[dl] + o] = e >> 7;
    }
}

// ---------------- W fragmentize + bf16 split (all 3 layers, one launch) ----------------
// Frag f = ((nh*2+p)*4+s)*4+nt; lane holds B[k=s*32+quad*8+j][n=nh*64+nt*16+(lane&15)]

__global__ void k_wfrag(const float* __restrict__ W0, const float* __restrict__ W1,
                        const float* __restrict__ W2, unsigned short* __restrict__ Wf0) {
    int l = blockIdx.x >> 6;
    int f = blockIdx.x & 63;
    int lane = threadIdx.x;
    const float* W = (l == 0) ? W0 : (l == 1) ? W1 : W2;
    unsigned short* Wf = Wf0 + (size_t)l * 32768;
    int nt = f & 3, s = (f >> 2) & 3, p = (f >> 4) & 1, nh = f >> 5;
    int n = nh * 64 + nt * 16 + (lane & 15);
    int kbase = s * 32 + (lane >> 4) * 8;
    unsigned short o[8];
#pragma unroll
    for (int j = 0; j < 8; ++j) {
        float w = W[(size_t)(kbase + j) * DH + n];
        unsigned short h = f2bf(w);
        o[j] = p ? f2bf(w - bf2f(h)) : h;
    }
    unsigned short* d = Wf + (size_t)f * 512 + lane * 8;
    *(ushort4*)d       = make_ushort4(o[0], o[1], o[2], o[3]);
    *(ushort4*)(d + 4) = make_ushort4(o[4], o[5], o[6], o[7]);
}

// ---------------- MFMA GEMM: hs_bf16 = bf16((X @ W) * dinv[row]) ----------------
// fp32 X staged in LDS; hi/lo bf16 split in-register; bf16x3 products.
// block = 256 thr (4 waves), tile 64 rows x 128 cols; wave (mh,nh) owns 32x64.

__launch_bounds__(256)
__global__ void k_gemm_mfma(const float* __restrict__ X,
                            const unsigned short* __restrict__ Wf,
                            const float* __restrict__ dinv,
                            unsigned short* __restrict__ hs, int N)
{
    __shared__ float As[64 * DH];   // 32 KB

    const int tid  = threadIdx.x;
    const int lane = tid & 63, wave = tid >> 6;
    const int mh = wave >> 1, nh = wave & 1;
    const int rowBase = blockIdx.x * 64;
    const int r15 = lane & 15, quad = lane >> 4;

    {
        const float4* gp = (const float4*)(X + (size_t)rowBase * DH);
        float4* sp = (float4*)As;
#pragma unroll
        for (int it = 0; it < 8; ++it) {
            int idx = it * 256 + tid;
            int grow = idx >> 5;
            float4 v = make_float4(0.f, 0.f, 0.f, 0.f);
            if (rowBase + grow < N) v = gp[idx];
            sp[idx] = v;
        }
    }
    __syncthreads();

    f32x4 acc[2][4];
#pragma unroll
    for (int mt = 0; mt < 2; ++mt)
#pragma unroll
        for (int nt = 0; nt < 4; ++nt)
            acc[mt][nt] = (f32x4){0.f, 0.f, 0.f, 0.f};

#pragma unroll
    for (int s = 0; s < 4; ++s) {
        short8 wfh[4], wfl[4];
#pragma unroll
        for (int nt = 0; nt < 4; ++nt) {
            wfh[nt] = *(const short8*)(Wf + ((((nh * 2 + 0) * 4 + s) * 4 + nt) * 512) + lane * 8);
            wfl[nt] = *(const short8*)(Wf + ((((nh * 2 + 1) * 4 + s) * 4 + nt) * 512) + lane * 8);
        }
#pragma unroll
        for (int mt = 0; mt < 2; ++mt) {
            const float* ap = As + (mh * 32 + mt * 16 + r15) * DH + s * 32 + quad * 8;
            short8 ah, al;
#pragma unroll
            for (int j = 0; j < 8; ++j) {
                float v = ap[j];
                unsigned short h = f2bf(v);
                ah[j] = (short)h;
                al[j] = (short)f2bf(v - bf2f(h));
            }
#pragma unroll
            for (int nt = 0; nt < 4; ++nt) {
                acc[mt][nt] = __builtin_amdgcn_mfma_f32_16x16x32_bf16(ah, wfh[nt], acc[mt][nt], 0, 0, 0);
                acc[mt][nt] = __builtin_amdgcn_mfma_f32_16x16x32_bf16(ah, wfl[nt], acc[mt][nt], 0, 0, 0);
                acc[mt][nt] = __builtin_amdgcn_mfma_f32_16x16x32_bf16(al, wfh[nt], acc[mt][nt], 0, 0, 0);
            }
        }
    }

    // epilogue: C/D layout col=lane&15, row=quad*4+reg
#pragma unroll
    for (int mt = 0; mt < 2; ++mt) {
        int rl = mh * 32 + mt * 16 + quad * 4;
#pragma unroll
        for (int reg = 0; reg < 4; ++reg) {
            int row = rowBase + rl + reg;
            if (row < N) {
                float sc = dinv[row];
#pragma unroll
                for (int nt = 0; nt < 4; ++nt)
                    hs[(size_t)row * DH + nh * 64 + nt * 16 + r15] = f2bf(acc[mt][nt][reg] * sc);
            }
        }
    }
}

// ---------------- gather v2: 2 nodes per wave (32 lanes each, ushort4 loads) ----------------

__launch_bounds__(256)
__global__ void k_gather(const unsigned short* __restrict__ hs, const int* __restrict__ rowptr,
                         const int* __restrict__ csr_src, const float* __restrict__ dinv,
                         const float* __restrict__ cb, const float* __restrict__ bm,
                         const float* __restrict__ bv, const float* __restrict__ bg,
                         const float* __restrict__ bb, const float* __restrict__ prev,
                         float* __restrict__ xout, int N)
{
    const int node = (blockIdx.x * blockDim.x + threadIdx.x) >> 5;   // half-wave id
    const int lh = threadIdx.x & 31;
    if (node >= N) return;
    const int f = lh * 4;
    const int e0 = rowptr[node], e1 = rowptr[node + 1];

    ushort4 su = *(const ushort4*)(hs + (size_t)node * DH + f);      // self-loop
    float a0 = bf2f(su.x), a1 = bf2f(su.y), a2 = bf2f(su.z), a3 = bf2f(su.w);

    for (int base = e0; base < e1; base += 32) {
        int cnt = e1 - base; if (cnt > 32) cnt = 32;
        int idx = (lh < cnt) ? csr_src[base + lh] : 0;
        int i = 0;
        for (; i + 4 <= cnt; i += 4) {
            int s0 = __shfl(idx, i,     32), s1 = __shfl(idx, i + 1, 32);
            int s2 = __shfl(idx, i + 2, 32), s3 = __shfl(idx, i + 3, 32);
            ushort4 v0 = *(const ushort4*)(hs + (size_t)s0 * DH + f);
            ushort4 v1 = *(const ushort4*)(hs + (size_t)s1 * DH + f);
            ushort4 v2 = *(const ushort4*)(hs + (size_t)s2 * DH + f);
            ushort4 v3 = *(const ushort4*)(hs + (size_t)s3 * DH + f);
            a0 += (bf2f(v0.x) + bf2f(v1.x)) + (bf2f(v2.x) + bf2f(v3.x));
            a1 += (bf2f(v0.y) + bf2f(v1.y)) + (bf2f(v2.y) + bf2f(v3.y));
            a2 += (bf2f(v0.z) + bf2f(v1.z)) + (bf2f(v2.z) + bf2f(v3.z));
            a3 += (bf2f(v0.w) + bf2f(v1.w)) + (bf2f(v2.w) + bf2f(v3.w));
        }
        for (; i < cnt; ++i) {
            int s = __shfl(idx, i, 32);
            ushort4 v = *(const ushort4*)(hs + (size_t)s * DH + f);
            a0 += bf2f(v.x); a1 += bf2f(v.y); a2 += bf2f(v.z); a3 += bf2f(v.w);
        }
    }

    const float sc = dinv[node];
    const float4 vcb = *(const float4*)(cb + f);
    const float4 vbm = *(const float4*)(bm + f);
    const float4 vbv = *(const float4*)(bv + f);
    const float4 vbg = *(const float4*)(bg + f);
    const float4 vbb = *(const float4*)(bb + f);
    float o0 = (a0 * sc + vcb.x - vbm.x) * rsqrtf(vbv.x + EPSB) * vbg.x + vbb.x;
    float o1 = (a1 * sc + vcb.y - vbm.y) * rsqrtf(vbv.y + EPSB) * vbg.y + vbb.y;
    float o2 = (a2 * sc + vcb.z - vbm.z) * rsqrtf(vbv.z + EPSB) * vbg.z + vbb.z;
    float o3 = (a3 * sc + vcb.w - vbm.w) * rsqrtf(vbv.w + EPSB) * vbg.w + vbb.w;
    o0 = fmaxf(o0, 0.f); o1 = fmaxf(o1, 0.f); o2 = fmaxf(o2, 0.f); o3 = fmaxf(o3, 0.f);
    if (prev) {
        const float4 p = *(const float4*)(prev + (size_t)node * DH + f);
        o0 += p.x; o1 += p.y; o2 += p.z; o3 += p.w;
    }
    *(float4*)(xout + (size_t)node * DH + f) = make_float4(o0, o1, o2, o3);
}

// ---------------- fused pool (mean+max) + 3-layer MLP head ----------------

__launch_bounds__(128)
__global__ void k_pool_mlp(const float* __restrict__ x, const int* __restrict__ starts,
                           const float* __restrict__ L1w, const float* __restrict__ L1b,
                           const float* __restrict__ L2w, const float* __restrict__ L2b,
                           const float* __restrict__ L3w, const float* __restrict__ L3b,
                           float* __restrict__ out)
{
    int g = blockIdx.x, t = threadIdx.x;
    int s0 = starts[g], s1 = starts[g + 1];
    float su0 = 0.f, su1 = 0.f, su2 = 0.f, su3 = 0.f;
    float m0 = -INFINITY, m1 = -INFINITY, m2 = -INFINITY, m3 = -INFINITY;
    int i = s0;
    for (; i + 4 <= s1; i += 4) {
        float v0 = x[(size_t)i * DH + t];
        float v1 = x[(size_t)(i + 1) * DH + t];
        float v2 = x[(size_t)(i + 2) * DH + t];
        float v3 = x[(size_t)(i + 3) * DH + t];
        su0 += v0; su1 += v1; su2 += v2; su3 += v3;
        m0 = fmaxf(m0, v0); m1 = fmaxf(m1, v1);
        m2 = fmaxf(m2, v2); m3 = fmaxf(m3, v3);
    }
    for (; i < s1; ++i) {
        float v = x[(size_t)i * DH + t];
        su0 += v; m0 = fmaxf(m0, v);
    }
    float sum = (su0 + su1) + (su2 + su3);
    float mx = fmaxf(fmaxf(m0, m1), fmaxf(m2, m3));

    __shared__ float h[256];
    h[t] = sum / (float)(s1 - s0);
    h[128 + t] = mx;
    __syncthreads();

    float a = L1b[t];
    for (int k = 0; k < 256; ++k) a += h[k] * L1w[k * DH + t];
    __shared__ float h1[128];
    h1[t] = fmaxf(a, 0.f);
    __syncthreads();

    __shared__ float h2[64];
    if (t < 64) {
        float a2 = L2b[t];
        for (int k = 0; k < 128; ++k) a2 += h1[k] * L2w[k * 64 + t];
        h2[t] = fmaxf(a2, 0.f);
    }
    __syncthreads();

    if (t < 64) {
        float p = h2[t] * L3w[t];
#pragma unroll
        for (int off = 32; off > 0; off >>= 1) p += __shfl_down(p, off, 64);
        if (t == 0) out[g] = p + L3b[0];
    }
}

// ---------------- launch ----------------

static inline char* align16(char* p) {
    return (char*)(((uintptr_t)p + 15) & ~(uintptr_t)15);
}

extern "C" void kernel_launch(void* const* d_in, const int* in_sizes, int n_in,
                              void* d_out, int out_size, void* d_ws, size_t ws_size,
                              hipStream_t stream)
{
    const float* x     = (const float*)d_in[0];
    const int*   ei    = (const int*)d_in[1];
    const int*   batch = (const int*)d_in[2];
    const int N = in_sizes[0] / DH;
    const int E = in_sizes[1] / 2;
    const int G = out_size;
    const int* src = ei;
    const int* dst = ei + E;

    const float* W[3]  = {(const float*)d_in[3],  (const float*)d_in[9],  (const float*)d_in[15]};
    const float* cb[3] = {(const float*)d_in[4],  (const float*)d_in[10], (const float*)d_in[16]};
    const float* bg[3] = {(const float*)d_in[5],  (const float*)d_in[11], (const float*)d_in[17]};
    const float* bt[3] = {(const float*)d_in[6],  (const float*)d_in[12], (const float*)d_in[18]};
    const float* bm[3] = {(const float*)d_in[7],  (const float*)d_in[13], (const float*)d_in[19]};
    const float* bv[3] = {(const float*)d_in[8],  (const float*)d_in[14], (const float*)d_in[20]};
    const float* L1w = (const float*)d_in[21]; const float* L1b = (const float*)d_in[22];
    const float* L2w = (const float*)d_in[23]; const float* L2b = (const float*)d_in[24];
    const float* L3w = (const float*)d_in[25]; const float* L3b = (const float*)d_in[26];

    char* wsp = (char*)d_ws;
    size_t big = (size_t)N * DH * sizeof(float);
    unsigned short* HS = (unsigned short*)wsp; wsp += (size_t)N * DH * sizeof(unsigned short);
    float* P1 = (float*)wsp;  wsp += big;
    float* P2 = (float*)wsp;  wsp += big;
    unsigned short* Wfrag = (unsigned short*)wsp; wsp += 3 * 65536;
    float* dinv   = (float*)wsp; wsp += (size_t)N * sizeof(float);
    int*   rowptr = (int*)wsp;   wsp = align16(wsp + (size_t)(N + 1) * sizeof(int));
    int*   csr_src= (int*)wsp;   wsp += (size_t)E * sizeof(int);
    int*   starts = (int*)wsp;   wsp = align16(wsp + (size_t)(G + 1) * sizeof(int));
    int*   gcur   = (int*)wsp;   wsp = align16(wsp + (size_t)MAXB * sizeof(int));
    int*   bbase  = (int*)wsp;   wsp = align16(wsp + (size_t)MAXB * sizeof(int));
    int*   bbuf   = (int*)wsp;   wsp += (size_t)MAXB * BCAP * sizeof(int);   // 10.2 MB

    const int NB = (N + 127) >> 7;
    const int nblkA = 128;
    const int chunk = (E + nblkA - 1) / nblkA;

    hipMemsetAsync(gcur, 0, (size_t)NB * sizeof(int), stream);
    k_bucketA<<<nblkA, 256, 0, stream>>>(src, dst, gcur, bbuf, E, NB, chunk);
    k_bgscan <<<1, 1024, 0, stream>>>(gcur, bbase, rowptr, NB, N, E);
    k_bfinal <<<NB, 256, 0, stream>>>(gcur, bbase, bbuf, rowptr, dinv, csr_src, N);
    k_bounds <<<(N + 255) / 256, 256, 0, stream>>>(batch, starts, N, G);
    k_wfrag  <<<192, 64, 0, stream>>>(W[0], W[1], W[2], Wfrag);

    // L0: gemm(x  -> HS); gather(HS, prev=null, out=P1)
    // L1: gemm(P1 -> HS); gather(HS, prev=P1,   out=P2)
    // L2: gemm(P2 -> HS); gather(HS, prev=P2,   out=P1)
    const float* Xs[3]    = {x, P1, P2};
    const float* prevb[3] = {nullptr, P1, P2};
    float* xoutb[3]       = {P1, P2, P1};

    int gemmGrid = (N + 63) / 64;
    int gathGrid = ((size_t)N * 32 + 255) / 256;

    for (int l = 0; l < 3; ++l) {
        k_gemm_mfma<<<gemmGrid, 256, 0, stream>>>(Xs[l], Wfrag + (size_t)l * 32768,
                                                  dinv, HS, N);
        k_gather<<<gathGrid, 256, 0, stream>>>(HS, rowptr, csr_src, dinv,
                                               cb[l], bm[l], bv[l], bg[l], bt[l],
                                               prevb[l], xoutb[l], N);
    }

    k_pool_mlp<<<G, 128, 0, stream>>>(xoutb[2], starts, L1w, L1b, L2w, L2b, L3w, L3b,
                                      (float*)d_out);
}